// Round 6
// baseline (443.226 us; speedup 1.0000x reference)
//
#include <hip/hip_runtime.h>
#include <hip/hip_bf16.h>
#include <math.h>

#define S_TOK 8192
#define M_DIM 1024
#define E_NUM 8
#define F_DIM 4096
#define CAP   1024

typedef short short8 __attribute__((ext_vector_type(8)));
typedef float f32x4 __attribute__((ext_vector_type(4)));
typedef unsigned short ushortx4 __attribute__((ext_vector_type(4)));

__device__ inline unsigned short f2bf(float f) {
    union { float f; unsigned int u; } v; v.f = f;
    unsigned int r = v.u + 0x7fffu + ((v.u >> 16) & 1u);
    return (unsigned short)(r >> 16);
}

// gelu(x) = 0.5 x (1 + tanh(y)), y = c(x + 0.044715 x^3) = x*e/(e+1), e=exp(2y)
__device__ inline float gelu_fast(float x) {
    float y = 0.7978845608028654f * (x + 0.044715f * x * x * x);
    if (y > 40.f) return x;
    float e = exp2f(2.8853900817779268f * y);
    return x * e / (e + 1.0f);
}

__device__ inline void gl_lds16(const void* g, void* l) {
    __builtin_amdgcn_global_load_lds(
        (const __attribute__((address_space(1))) unsigned int*)g,
        (__attribute__((address_space(3))) unsigned int*)l, 16, 0, 0);
}

// ---------------- gating ----------------
__global__ __launch_bounds__(256) void gating_kernel(
    const float* __restrict__ x, const float* __restrict__ wg,
    int* __restrict__ idx, float* __restrict__ gate)
{
    int wid = threadIdx.x >> 6;
    int lane = threadIdx.x & 63;
    int s = blockIdx.x * 4 + wid;
    const float* xs = x + (size_t)s * M_DIM;

    double acc[E_NUM];
#pragma unroll
    for (int e = 0; e < E_NUM; e++) acc[e] = 0.0;

    for (int i = lane; i < M_DIM; i += 64) {
        float xv = xs[i];
        float4 wa = *(const float4*)(wg + (size_t)i * E_NUM);
        float4 wb = *(const float4*)(wg + (size_t)i * E_NUM + 4);
        acc[0] += (double)xv * (double)wa.x;
        acc[1] += (double)xv * (double)wa.y;
        acc[2] += (double)xv * (double)wa.z;
        acc[3] += (double)xv * (double)wa.w;
        acc[4] += (double)xv * (double)wb.x;
        acc[5] += (double)xv * (double)wb.y;
        acc[6] += (double)xv * (double)wb.z;
        acc[7] += (double)xv * (double)wb.w;
    }
#pragma unroll
    for (int e = 0; e < E_NUM; e++) {
        double v = acc[e];
        for (int o = 32; o > 0; o >>= 1) v += __shfl_down(v, o, 64);
        acc[e] = v;
    }
    if (lane == 0) {
        double mx = acc[0]; int am = 0;
#pragma unroll
        for (int e = 1; e < E_NUM; e++) {
            if (acc[e] > mx) { mx = acc[e]; am = e; }
        }
        double se = 0.0;
#pragma unroll
        for (int e = 0; e < E_NUM; e++) se += exp(acc[e] - mx);
        idx[s] = am;
        gate[s] = (float)(1.0 / se);
    }
}

// ---------------- scan: token-order slot assignment ----------------
__global__ __launch_bounds__(1024) void scan_build(
    const int* __restrict__ idx, int* __restrict__ srcmap)
{
    __shared__ unsigned int sc[2][4][1024];
    int t = threadIdx.x;

    for (int i = t; i < E_NUM * CAP; i += 1024) srcmap[i] = -1;

    int eid[8];
    unsigned int cnt[E_NUM];
#pragma unroll
    for (int e = 0; e < E_NUM; e++) cnt[e] = 0;
#pragma unroll
    for (int i = 0; i < 8; i++) {
        int e = idx[t * 8 + i];
        eid[i] = e;
        cnt[e]++;
    }
    unsigned int pk[4];
#pragma unroll
    for (int i = 0; i < 4; i++) pk[i] = cnt[2 * i] | (cnt[2 * i + 1] << 16);
#pragma unroll
    for (int i = 0; i < 4; i++) sc[0][i][t] = pk[i];

    int buf = 0;
    for (int ofs = 1; ofs < 1024; ofs <<= 1) {
        __syncthreads();
        unsigned int v[4];
#pragma unroll
        for (int i = 0; i < 4; i++) {
            v[i] = sc[buf][i][t] + ((t >= ofs) ? sc[buf][i][t - ofs] : 0u);
            sc[buf ^ 1][i][t] = v[i];
        }
        buf ^= 1;
    }
    __syncthreads();
    unsigned int pos[E_NUM];
#pragma unroll
    for (int e = 0; e < E_NUM; e++) {
        unsigned int incl = (sc[buf][e >> 1][t] >> ((e & 1) * 16)) & 0xffffu;
        pos[e] = incl - cnt[e];
    }
#pragma unroll
    for (int i = 0; i < 8; i++) {
        int e = eid[i];
        unsigned int p = pos[e]++;
        if (p < CAP) srcmap[e * CAP + p] = t * 8 + i;
    }
}

// ---------------- dispatch: gather rows -> bf16 A1 [E*C][M] ----------------
__global__ __launch_bounds__(256) void dispatch_kernel(
    const float* __restrict__ x, const int* __restrict__ srcmap,
    unsigned short* __restrict__ A1)
{
    int slot = blockIdx.x;
    int s = srcmap[slot];
    int t = threadIdx.x;
    ushortx4 o;
    if (s >= 0) {
        float4 v = ((const float4*)(x + (size_t)s * M_DIM))[t];
        o[0] = f2bf(v.x); o[1] = f2bf(v.y); o[2] = f2bf(v.z); o[3] = f2bf(v.w);
    } else {
        o[0] = 0; o[1] = 0; o[2] = 0; o[3] = 0;
    }
    __builtin_nontemporal_store(o, (ushortx4*)(A1 + (size_t)slot * M_DIM) + t);
}

// ---------------- transpose + cvt ----------------
__global__ __launch_bounds__(256) void transpose_cvt(
    const float* __restrict__ in, unsigned short* __restrict__ out, int R, int Cc)
{
    __shared__ float tile[32][33];
    int e = blockIdx.z;
    int br = blockIdx.y * 32, bc = blockIdx.x * 32;
    const float* ine = in + (size_t)e * R * Cc;
    unsigned short* oute = out + (size_t)e * R * Cc;
    int tx = threadIdx.x, ty = threadIdx.y;
#pragma unroll
    for (int i = 0; i < 32; i += 8)
        tile[ty + i][tx] = ine[(size_t)(br + ty + i) * Cc + (bc + tx)];
    __syncthreads();
#pragma unroll
    for (int i = 0; i < 32; i += 8)
        __builtin_nontemporal_store(f2bf(tile[tx][ty + i]),
            &oute[(size_t)(bc + ty + i) * R + (br + tx)]);
}

// ---------------- 128x128 BK=64 double-buffered bf16 MFMA GEMM ----------------
// 4 waves (2x2), 64 KiB LDS -> 2 blocks/CU. Conflict-free involution swizzle
// (round-5, verified 0 bank conflicts). NEW in round 6: L2 super-tiled block
// ordering (per-XCD working set < 4 MiB) + non-temporal output stores.
// MODE 0 (GEMM1): K=1024, NB=4096: OutH = bf16(gelu(acc+bias)).
// MODE 1 (GEMM2): K=4096, NB=1024: out[s] = gate[s]*(acc+bias), row scatter.
template <int MODE>
__global__ __launch_bounds__(256, 2) void gemm128(
    const unsigned short* __restrict__ A, const unsigned short* __restrict__ B,
    const float* __restrict__ bias, unsigned short* __restrict__ OutH,
    float* __restrict__ OutF, const int* __restrict__ srcmap,
    const float* __restrict__ gate)
{
    constexpr int K   = (MODE == 0) ? 1024 : 4096;
    constexpr int NB  = (MODE == 0) ? 4096 : 1024;
    constexpr int NT  = K / 64;
    constexpr int NWG = (MODE == 0) ? 2048 : 512;

    __shared__ __align__(16) unsigned short LA[2][8192];  // [buf][row*64 + slot*8 + j]
    __shared__ __align__(16) unsigned short LB[2][8192];

    int bid = blockIdx.x;
    int swz = (bid & 7) * (NWG / 8) + (bid >> 3);   // XCD-contiguous (NWG%8==0)
    int e, tm, tn;
    if (MODE == 0) {
        // per-XCD (= per-expert): 2 passes of {4 tm} x {32 tn}, tm-quad inner.
        // Active L2 footprint: 4 A-panels (1MB, pass-resident) + ~2 B panels.
        e = swz >> 8;
        int local = swz & 255;
        int p = local >> 7;
        int r = local & 127;
        tn = r >> 2;
        tm = p * 4 + (r & 3);
    } else {
        // per-XCD (= per-expert): 2x2 clusters of 1MB panels (4MB footprint).
        e = swz >> 6;
        int local = swz & 63;
        int c = local >> 2, i = local & 3;
        tm = (c >> 2) * 2 + (i >> 1);
        tn = (c & 3) * 2 + (i & 1);
    }

    const unsigned short* Ae = A + ((size_t)e * CAP + (size_t)tm * 128) * K;
    const unsigned short* Be = B + ((size_t)e * NB + (size_t)tn * 128) * K;

    int tid = threadIdx.x, w = tid >> 6, lane = tid & 63;
    int wm = w >> 1, wn = w & 1;
    int fr = lane & 15, kq = lane >> 4;
    int r0 = wm * 64, c0 = wn * 64;

    // ---- staging: wave w instr i covers rows w*32+i*8..+8, 8 chunk slots ----
    // LDS slot (lane&7) receives logical chunk (lane&7)^(lane>>3) (involution).
    int lr = lane >> 3;
    int lc = (lane & 7) ^ lr;
    const unsigned short* gA[4]; const unsigned short* gB[4]; int dL[4];
#pragma unroll
    for (int i = 0; i < 4; i++) {
        int rb = w * 32 + i * 8;
        gA[i] = Ae + (size_t)(rb + lr) * K + lc * 8;
        gB[i] = Be + (size_t)(rb + lr) * K + lc * 8;
        dL[i] = rb * 64;
    }

#define STAGE(bf, t_) do { int k0_ = (t_) * 64;                      \
    gl_lds16(gA[0] + k0_, &LA[bf][dL[0]]);                           \
    gl_lds16(gA[1] + k0_, &LA[bf][dL[1]]);                           \
    gl_lds16(gA[2] + k0_, &LA[bf][dL[2]]);                           \
    gl_lds16(gA[3] + k0_, &LA[bf][dL[3]]);                           \
    gl_lds16(gB[0] + k0_, &LB[bf][dL[0]]);                           \
    gl_lds16(gB[1] + k0_, &LB[bf][dL[1]]);                           \
    gl_lds16(gB[2] + k0_, &LB[bf][dL[2]]);                           \
    gl_lds16(gB[3] + k0_, &LB[bf][dL[3]]);                           \
} while (0)

    // ---- fragment read offsets (swizzled; conflict-free, measured r5) ----
    int sw0 = ((kq)     ^ (fr & 7)) * 8;    // ks=0 chunk
    int sw1 = ((4 + kq) ^ (fr & 7)) * 8;    // ks=1 chunk
    int aBase = (r0 + fr) * 64;
    int bBase = (c0 + fr) * 64;

    f32x4 acc[4][4];
#pragma unroll
    for (int i = 0; i < 4; i++)
#pragma unroll
        for (int j = 0; j < 4; j++) acc[i][j] = (f32x4){0.f, 0.f, 0.f, 0.f};

    STAGE(0, 0);
    asm volatile("s_waitcnt vmcnt(0)" ::: "memory");
    __builtin_amdgcn_s_barrier();

    int cur = 0;
    for (int t = 0; t < NT; ++t) {
        if (t + 1 < NT) STAGE(cur ^ 1, t + 1);

        short8 a[4][2], b[4][2];
#pragma unroll
        for (int mi = 0; mi < 4; mi++) {
            a[mi][0] = *(const short8*)&LA[cur][aBase + mi * 1024 + sw0];
            a[mi][1] = *(const short8*)&LA[cur][aBase + mi * 1024 + sw1];
        }
#pragma unroll
        for (int ni = 0; ni < 4; ni++) {
            b[ni][0] = *(const short8*)&LB[cur][bBase + ni * 1024 + sw0];
            b[ni][1] = *(const short8*)&LB[cur][bBase + ni * 1024 + sw1];
        }
        __builtin_amdgcn_s_setprio(1);
#pragma unroll
        for (int ks = 0; ks < 2; ks++)
#pragma unroll
            for (int mi = 0; mi < 4; mi++)
#pragma unroll
                for (int ni = 0; ni < 4; ni++)
                    acc[mi][ni] = __builtin_amdgcn_mfma_f32_16x16x32_bf16(
                        a[mi][ks], b[ni][ks], acc[mi][ni], 0, 0, 0);
        __builtin_amdgcn_s_setprio(0);

        if (t + 1 < NT) asm volatile("s_waitcnt vmcnt(0)" ::: "memory");
        __builtin_amdgcn_s_barrier();
        cur ^= 1;
    }
#undef STAGE

    if (MODE == 0) {
        // swizzled repack (128x128 bf16 = 32KB in LA area) -> coalesced nt 16B stores
        __syncthreads();
        unsigned short* R = (unsigned short*)LA;
        float bv[4];
#pragma unroll
        for (int ni = 0; ni < 4; ni++)
            bv[ni] = bias[e * NB + tn * 128 + c0 + ni * 16 + fr];
#pragma unroll
        for (int mi = 0; mi < 4; mi++) {
#pragma unroll
            for (int j = 0; j < 4; j++) {
                int row = r0 + mi * 16 + kq * 4 + j;
#pragma unroll
                for (int ni = 0; ni < 4; ni++) {
                    int col = c0 + ni * 16 + fr;
                    R[row * 128 + (((col >> 3) ^ (row & 7)) << 3) + (col & 7)] =
                        f2bf(gelu_fast(acc[mi][ni][j] + bv[ni]));
                }
            }
        }
        __syncthreads();
        int row = tid >> 1, seg = tid & 1;
        size_t gb = ((size_t)(e * CAP + tm * 128 + row)) * NB + tn * 128 + seg * 64;
#pragma unroll
        for (int i = 0; i < 8; i++) {
            int chunk = seg * 8 + i;
            short8 v = *(const short8*)&R[row * 128 + ((chunk ^ (row & 7)) << 3)];
            __builtin_nontemporal_store(v, (short8*)&OutH[gb + i * 8]);
        }
    } else {
        // fused combine: out[s] = gate[s]*(acc + b2), row scatter (nt stores)
        float bv[4];
#pragma unroll
        for (int ni = 0; ni < 4; ni++)
            bv[ni] = bias[e * NB + tn * 128 + c0 + ni * 16 + fr];
#pragma unroll
        for (int mi = 0; mi < 4; mi++) {
#pragma unroll
            for (int j = 0; j < 4; j++) {
                int r = tm * 128 + r0 + mi * 16 + kq * 4 + j;
                int s = srcmap[e * CAP + r];
                if (s < 0) continue;
                float g = gate[s];
                float* ob = OutF + (size_t)s * NB + tn * 128 + c0;
#pragma unroll
                for (int ni = 0; ni < 4; ni++)
                    __builtin_nontemporal_store(g * (acc[mi][ni][j] + bv[ni]),
                                                &ob[ni * 16 + fr]);
            }
        }
    }
}

extern "C" void kernel_launch(void* const* d_in, const int* in_sizes, int n_in,
                              void* d_out, int out_size, void* d_ws, size_t ws_size,
                              hipStream_t stream) {
    const float* x  = (const float*)d_in[0];  // [S, M]
    const float* wg = (const float*)d_in[1];  // [M, E]
    const float* w1 = (const float*)d_in[2];  // [E, M, F]
    const float* b1 = (const float*)d_in[3];  // [E, F]
    const float* w2 = (const float*)d_in[4];  // [E, F, M]
    const float* b2 = (const float*)d_in[5];  // [E, M]
    float* out = (float*)d_out;

    char* ws = (char*)d_ws;
    unsigned short* A1  = (unsigned short*)(ws);                       // 16 MiB [E*C][M]
    unsigned short* W1T = (unsigned short*)(ws + (size_t)(16u << 20)); // 64 MiB [E][F][M]
    unsigned short* W2T = (unsigned short*)(ws + (size_t)(80u << 20)); // 64 MiB [E][M][F]
    unsigned short* H   = (unsigned short*)(ws + (size_t)(144u << 20));// 64 MiB [E][C][F]
    int*   idx  = (int*)(ws + (size_t)(208u << 20));
    float* gate = (float*)(ws + (size_t)(208u << 20) + 32768);
    int*   srcm = (int*)(ws + (size_t)(208u << 20) + 65536);

    hipMemsetAsync(d_out, 0, (size_t)S_TOK * M_DIM * sizeof(float), stream);

    gating_kernel<<<S_TOK / 4, 256, 0, stream>>>(x, wg, idx, gate);
    scan_build<<<1, 1024, 0, stream>>>(idx, srcm);
    dispatch_kernel<<<E_NUM * CAP, 256, 0, stream>>>(x, srcm, A1);
    transpose_cvt<<<dim3(F_DIM / 32, M_DIM / 32, E_NUM), dim3(32, 8), 0, stream>>>(
        w1, W1T, M_DIM, F_DIM);
    transpose_cvt<<<dim3(M_DIM / 32, F_DIM / 32, E_NUM), dim3(32, 8), 0, stream>>>(
        w2, W2T, F_DIM, M_DIM);

    // GEMM1: H = gelu(A1 @ w1 + b1)  [E][1024][4096], K=1024; 2048 blocks
    gemm128<0><<<2048, 256, 0, stream>>>(A1, W1T, b1, H, nullptr, nullptr, nullptr);

    // GEMM2: out[s] = gate[s]*(H @ w2 + b2)  K=4096; 512 blocks, fused combine
    gemm128<1><<<512, 256, 0, stream>>>(H, W2T, b2, nullptr, out, srcm, gate);
}

// Round 7
// 355.974 us; speedup vs baseline: 1.2451x; 1.2451x over previous
//
#include <hip/hip_runtime.h>
#include <hip/hip_bf16.h>
#include <math.h>

#define S_TOK 8192
#define M_DIM 1024
#define E_NUM 8
#define F_DIM 4096
#define CAP   1024

typedef short short8 __attribute__((ext_vector_type(8)));
typedef float f32x4 __attribute__((ext_vector_type(4)));
typedef unsigned short ushortx4 __attribute__((ext_vector_type(4)));

__device__ inline unsigned short f2bf(float f) {
    union { float f; unsigned int u; } v; v.f = f;
    unsigned int r = v.u + 0x7fffu + ((v.u >> 16) & 1u);
    return (unsigned short)(r >> 16);
}

// gelu(x) = 0.5 x (1 + tanh(y)), y = c(x + 0.044715 x^3) = x*e/(e+1), e=exp(2y)
__device__ inline float gelu_fast(float x) {
    float y = 0.7978845608028654f * (x + 0.044715f * x * x * x);
    if (y > 40.f) return x;
    float e = exp2f(2.8853900817779268f * y);
    return x * e / (e + 1.0f);
}

__device__ inline void gl_lds16(const void* g, void* l) {
    __builtin_amdgcn_global_load_lds(
        (const __attribute__((address_space(1))) unsigned int*)g,
        (__attribute__((address_space(3))) unsigned int*)l, 16, 0, 0);
}

// ---------------- gating ----------------
__global__ __launch_bounds__(256) void gating_kernel(
    const float* __restrict__ x, const float* __restrict__ wg,
    int* __restrict__ idx, float* __restrict__ gate)
{
    int wid = threadIdx.x >> 6;
    int lane = threadIdx.x & 63;
    int s = blockIdx.x * 4 + wid;
    const float* xs = x + (size_t)s * M_DIM;

    double acc[E_NUM];
#pragma unroll
    for (int e = 0; e < E_NUM; e++) acc[e] = 0.0;

    for (int i = lane; i < M_DIM; i += 64) {
        float xv = xs[i];
        float4 wa = *(const float4*)(wg + (size_t)i * E_NUM);
        float4 wb = *(const float4*)(wg + (size_t)i * E_NUM + 4);
        acc[0] += (double)xv * (double)wa.x;
        acc[1] += (double)xv * (double)wa.y;
        acc[2] += (double)xv * (double)wa.z;
        acc[3] += (double)xv * (double)wa.w;
        acc[4] += (double)xv * (double)wb.x;
        acc[5] += (double)xv * (double)wb.y;
        acc[6] += (double)xv * (double)wb.z;
        acc[7] += (double)xv * (double)wb.w;
    }
#pragma unroll
    for (int e = 0; e < E_NUM; e++) {
        double v = acc[e];
        for (int o = 32; o > 0; o >>= 1) v += __shfl_down(v, o, 64);
        acc[e] = v;
    }
    if (lane == 0) {
        double mx = acc[0]; int am = 0;
#pragma unroll
        for (int e = 1; e < E_NUM; e++) {
            if (acc[e] > mx) { mx = acc[e]; am = e; }
        }
        double se = 0.0;
#pragma unroll
        for (int e = 0; e < E_NUM; e++) se += exp(acc[e] - mx);
        idx[s] = am;
        gate[s] = (float)(1.0 / se);
    }
}

// ---------------- scan: token-order slot assignment ----------------
__global__ __launch_bounds__(1024) void scan_build(
    const int* __restrict__ idx, int* __restrict__ srcmap)
{
    __shared__ unsigned int sc[2][4][1024];
    int t = threadIdx.x;

    for (int i = t; i < E_NUM * CAP; i += 1024) srcmap[i] = -1;

    int eid[8];
    unsigned int cnt[E_NUM];
#pragma unroll
    for (int e = 0; e < E_NUM; e++) cnt[e] = 0;
#pragma unroll
    for (int i = 0; i < 8; i++) {
        int e = idx[t * 8 + i];
        eid[i] = e;
        cnt[e]++;
    }
    unsigned int pk[4];
#pragma unroll
    for (int i = 0; i < 4; i++) pk[i] = cnt[2 * i] | (cnt[2 * i + 1] << 16);
#pragma unroll
    for (int i = 0; i < 4; i++) sc[0][i][t] = pk[i];

    int buf = 0;
    for (int ofs = 1; ofs < 1024; ofs <<= 1) {
        __syncthreads();
        unsigned int v[4];
#pragma unroll
        for (int i = 0; i < 4; i++) {
            v[i] = sc[buf][i][t] + ((t >= ofs) ? sc[buf][i][t - ofs] : 0u);
            sc[buf ^ 1][i][t] = v[i];
        }
        buf ^= 1;
    }
    __syncthreads();
    unsigned int pos[E_NUM];
#pragma unroll
    for (int e = 0; e < E_NUM; e++) {
        unsigned int incl = (sc[buf][e >> 1][t] >> ((e & 1) * 16)) & 0xffffu;
        pos[e] = incl - cnt[e];
    }
#pragma unroll
    for (int i = 0; i < 8; i++) {
        int e = eid[i];
        unsigned int p = pos[e]++;
        if (p < CAP) srcmap[e * CAP + p] = t * 8 + i;
    }
}

// ---------------- dispatch: gather rows -> bf16 A1 [E*C][M] ----------------
__global__ __launch_bounds__(256) void dispatch_kernel(
    const float* __restrict__ x, const int* __restrict__ srcmap,
    unsigned short* __restrict__ A1)
{
    int slot = blockIdx.x;
    int s = srcmap[slot];
    int t = threadIdx.x;
    ushortx4 o;
    if (s >= 0) {
        float4 v = ((const float4*)(x + (size_t)s * M_DIM))[t];
        o[0] = f2bf(v.x); o[1] = f2bf(v.y); o[2] = f2bf(v.z); o[3] = f2bf(v.w);
    } else {
        o[0] = 0; o[1] = 0; o[2] = 0; o[3] = 0;
    }
    ((ushortx4*)(A1 + (size_t)slot * M_DIM))[t] = o;
}

// ---------------- transpose + cvt ----------------
__global__ __launch_bounds__(256) void transpose_cvt(
    const float* __restrict__ in, unsigned short* __restrict__ out, int R, int Cc)
{
    __shared__ float tile[32][33];
    int e = blockIdx.z;
    int br = blockIdx.y * 32, bc = blockIdx.x * 32;
    const float* ine = in + (size_t)e * R * Cc;
    unsigned short* oute = out + (size_t)e * R * Cc;
    int tx = threadIdx.x, ty = threadIdx.y;
#pragma unroll
    for (int i = 0; i < 32; i += 8)
        tile[ty + i][tx] = ine[(size_t)(br + ty + i) * Cc + (bc + tx)];
    __syncthreads();
#pragma unroll
    for (int i = 0; i < 32; i += 8)
        oute[(size_t)(bc + ty + i) * R + (br + tx)] = f2bf(tile[tx][ty + i]);
}

// ---------------- 8-phase deep-pipelined bf16 MFMA GEMM (m201-style) ----------------
// 8 waves (2M x 4N), BK=64, 2-slot LDS dbuf. Per iteration: 2 K-tiles, 8 phases.
// Each phase: {ds_read quadrant frags | stage ONE half-tile | MFMA | barrier};
// counted vmcnt(2) only at phases 3 and 7. Conflict-free involution swizzle
// (r5-verified, 0 conflicts): phys chunk = logical ^ (row&7), both sides.
// MODE 0 (GEMM1): 256x256, K=1024, NB=4096: OutH = bf16(gelu(acc+bias)).
// MODE 1 (GEMM2): 256x128, K=4096, NB=1024: out[s] = gate[s]*(acc+b2), scatter.
template <int MODE>
__global__ __launch_bounds__(512, 1) void gemm8p(
    const unsigned short* __restrict__ A, const unsigned short* __restrict__ B,
    const float* __restrict__ bias, unsigned short* __restrict__ OutH,
    float* __restrict__ OutF, const int* __restrict__ srcmap,
    const float* __restrict__ gate)
{
    constexpr int K     = (MODE == 0) ? 1024 : 4096;
    constexpr int NB    = (MODE == 0) ? 4096 : 1024;
    constexpr int BN    = (MODE == 0) ? 256 : 128;
    constexpr int NT    = K / 64;
    constexpr int TNn   = NB / BN;              // 16 or 8
    constexpr int NWG   = E_NUM * 4 * TNn;      // 512 or 256
    constexpr int NI    = BN / 64;              // 4 or 2
    constexpr int NIH   = NI / 2;               // 2 or 1
    constexpr int WN    = BN / 4;               // per-wave col strip
    constexpr int AELEM = 256 * 64;             // per-slot A elems
    constexpr int BELEM = BN * 64;              // per-slot B elems
    constexpr int BOFF  = 2 * AELEM;

    __shared__ __align__(16) unsigned short LDS[BOFF + 2 * BELEM];

    int bid = blockIdx.x;
    int swz = (bid & 7) * (NWG / 8) + (bid >> 3);
    int e, tm, tn;
    {
        int per_e = 4 * TNn;
        e = swz / per_e;
        int rem = swz % per_e;
        tn = rem >> 2;
        tm = rem & 3;
    }

    const unsigned short* Ae = A + ((size_t)e * CAP + (size_t)tm * 256) * K;
    const unsigned short* Be = B + ((size_t)e * NB + (size_t)tn * BN) * K;

    int tid = threadIdx.x, w = tid >> 6, lane = tid & 63;
    int wm = w >> 2, wn = w & 3;
    int fr = lane & 15, kq = lane >> 4;

    // ---- staging addressing (pre-swizzled global source, linear LDS dest) ----
    int lr = lane >> 3;
    int lc8 = (lane & 7) ^ lr;
    const unsigned short *aS00, *aS01, *aS10, *aS11;
    const unsigned short *bS00, *bS01, *bS10, *bS11;
    int aD00, aD01, aD10, aD11, bD00, bD01, bD10, bD11;
    aS00 = Ae + (size_t)(w * 8 + lr) * K + lc8 * 8;         aD00 = (w * 8) * 64;
    aS01 = Ae + (size_t)(64 + w * 8 + lr) * K + lc8 * 8;    aD01 = (64 + w * 8) * 64;
    aS10 = Ae + (size_t)(128 + w * 8 + lr) * K + lc8 * 8;   aD10 = (128 + w * 8) * 64;
    aS11 = Ae + (size_t)(192 + w * 8 + lr) * K + lc8 * 8;   aD11 = (192 + w * 8) * 64;
    if (MODE == 0) {
        bS00 = Be + (size_t)(w * 8 + lr) * K + lc8 * 8;         bD00 = (w * 8) * 64;
        bS01 = Be + (size_t)(64 + w * 8 + lr) * K + lc8 * 8;    bD01 = (64 + w * 8) * 64;
        bS10 = Be + (size_t)(128 + w * 8 + lr) * K + lc8 * 8;   bD10 = (128 + w * 8) * 64;
        bS11 = Be + (size_t)(192 + w * 8 + lr) * K + lc8 * 8;   bD11 = (192 + w * 8) * 64;
    } else {
        bS00 = Be + (size_t)(w * 8 + lr) * K + lc8 * 8;         bD00 = (w * 8) * 64;
        bS01 = bS00;                                            bD01 = 0;
        bS10 = Be + (size_t)(64 + w * 8 + lr) * K + lc8 * 8;    bD10 = (64 + w * 8) * 64;
        bS11 = bS10;                                            bD11 = 0;
    }

#define STG_A(SL, H, T_) do {                                                  \
    gl_lds16(aS##H##0 + (size_t)(T_) * 64, &LDS[(SL) * AELEM + aD##H##0]);     \
    gl_lds16(aS##H##1 + (size_t)(T_) * 64, &LDS[(SL) * AELEM + aD##H##1]); } while (0)
#define STG_B(SL, H, T_) do {                                                  \
    gl_lds16(bS##H##0 + (size_t)(T_) * 64, &LDS[BOFF + (SL) * BELEM + bD##H##0]); \
    if (MODE == 0)                                                             \
        gl_lds16(bS##H##1 + (size_t)(T_) * 64, &LDS[BOFF + (SL) * BELEM + bD##H##1]); } while (0)

    // ---- fragment read swizzle (row&7 == fr&7 for all frags) ----
    int rsw = fr & 7;
    int swk0 = (kq ^ rsw) * 8;
    int swk1 = ((4 + kq) ^ rsw) * 8;

    short8 af[4][2];
    short8 bf[NIH][2];
    f32x4 acc[8][NI];
#pragma unroll
    for (int i = 0; i < 8; i++)
#pragma unroll
        for (int j = 0; j < NI; j++) acc[i][j] = (f32x4){0.f, 0.f, 0.f, 0.f};

#define READ_A(TS, MH) do {                                                    \
    _Pragma("unroll") for (int m2 = 0; m2 < 4; m2++) {                         \
        int row_ = wm * 128 + ((MH) * 4 + m2) * 16 + fr;                       \
        int b_ = (TS) * AELEM + row_ * 64;                                     \
        af[m2][0] = *(const short8*)&LDS[b_ + swk0];                           \
        af[m2][1] = *(const short8*)&LDS[b_ + swk1]; } } while (0)
#define READ_B(TS, NH) do {                                                    \
    _Pragma("unroll") for (int n2 = 0; n2 < NIH; n2++) {                       \
        int row_ = wn * WN + ((NH) * NIH + n2) * 16 + fr;                      \
        int b_ = BOFF + (TS) * BELEM + row_ * 64;                              \
        bf[n2][0] = *(const short8*)&LDS[b_ + swk0];                           \
        bf[n2][1] = *(const short8*)&LDS[b_ + swk1]; } } while (0)
#define DO_MFMA(MH, NH) do {                                                   \
    __builtin_amdgcn_s_setprio(1);                                             \
    _Pragma("unroll") for (int m2 = 0; m2 < 4; m2++)                           \
    _Pragma("unroll") for (int n2 = 0; n2 < NIH; n2++) {                       \
        acc[(MH)*4+m2][(NH)*NIH+n2] = __builtin_amdgcn_mfma_f32_16x16x32_bf16( \
            af[m2][0], bf[n2][0], acc[(MH)*4+m2][(NH)*NIH+n2], 0, 0, 0);       \
        acc[(MH)*4+m2][(NH)*NIH+n2] = __builtin_amdgcn_mfma_f32_16x16x32_bf16( \
            af[m2][1], bf[n2][1], acc[(MH)*4+m2][(NH)*NIH+n2], 0, 0, 0); }     \
    __builtin_amdgcn_s_setprio(0);                                             \
} while (0)
#define BAR() __builtin_amdgcn_s_barrier()

    // prologue: tile0 full + tile1 Ah0
    STG_A(0, 0, 0); STG_A(0, 1, 0); STG_B(0, 0, 0); STG_B(0, 1, 0);
    STG_A(1, 0, 1);
    asm volatile("s_waitcnt vmcnt(2)" ::: "memory");
    BAR();

#pragma unroll 1
    for (int i = 0; i < NT / 2; ++i) {
        const int T = 2 * i;
        const bool g2 = (T + 2 < NT), g3 = (T + 3 < NT);
        // p0: tile T, quad(mh0,nh0); stage (T+1)Ah1 -> slot1
        READ_A(0, 0); READ_B(0, 0);
        STG_A(1, 1, T + 1);
        DO_MFMA(0, 0);
        BAR();
        // p1: quad(mh0,nh1); stage (T+1)Bh0
        READ_B(0, 1);
        STG_B(1, 0, T + 1);
        DO_MFMA(0, 1);
        BAR();
        // p2: quad(mh1,nh0); stage (T+1)Bh1
        READ_A(0, 1); READ_B(0, 0);
        STG_B(1, 1, T + 1);
        DO_MFMA(1, 0);
        BAR();
        // p3: quad(mh1,nh1); stage (T+2)Ah0 -> slot0; vmcnt -> T+1 ready
        READ_B(0, 1);
        if (g2) STG_A(0, 0, T + 2);
        DO_MFMA(1, 1);
        if (g2) asm volatile("s_waitcnt vmcnt(2)" ::: "memory");
        else    asm volatile("s_waitcnt vmcnt(0)" ::: "memory");
        BAR();
        // p4: tile T+1, quad(mh0,nh0); stage (T+2)Ah1
        READ_A(1, 0); READ_B(1, 0);
        if (g2) STG_A(0, 1, T + 2);
        DO_MFMA(0, 0);
        BAR();
        // p5: quad(mh0,nh1); stage (T+2)Bh0
        READ_B(1, 1);
        if (g2) STG_B(0, 0, T + 2);
        DO_MFMA(0, 1);
        BAR();
        // p6: quad(mh1,nh0); stage (T+2)Bh1
        READ_A(1, 1); READ_B(1, 0);
        if (g2) STG_B(0, 1, T + 2);
        DO_MFMA(1, 0);
        BAR();
        // p7: quad(mh1,nh1); stage (T+3)Ah0 -> slot1; vmcnt -> T+2 ready
        READ_B(1, 1);
        if (g3) STG_A(1, 0, T + 3);
        DO_MFMA(1, 1);
        if (g3) asm volatile("s_waitcnt vmcnt(2)" ::: "memory");
        else    asm volatile("s_waitcnt vmcnt(0)" ::: "memory");
        BAR();
    }
#undef STG_A
#undef STG_B
#undef READ_A
#undef READ_B
#undef DO_MFMA
#undef BAR

    if (MODE == 0) {
        // epilogue: gelu+bias -> swizzled LDS repack (256x256 bf16 = 128KB) -> 16B stores
        unsigned short* R = (unsigned short*)LDS;
        float bv[NI];
#pragma unroll
        for (int ni = 0; ni < NI; ni++)
            bv[ni] = bias[e * NB + tn * BN + wn * WN + ni * 16 + fr];
#pragma unroll
        for (int mi = 0; mi < 8; mi++) {
#pragma unroll
            for (int j = 0; j < 4; j++) {
                int row = wm * 128 + mi * 16 + kq * 4 + j;
#pragma unroll
                for (int ni = 0; ni < NI; ni++) {
                    int col = wn * WN + ni * 16 + fr;
                    R[row * 256 + (((col >> 3) ^ (row & 7)) << 3) + (col & 7)] =
                        f2bf(gelu_fast(acc[mi][ni][j] + bv[ni]));
                }
            }
        }
        __syncthreads();
        int row = tid >> 1, seg = tid & 1;
        size_t gb = ((size_t)(e * CAP + tm * 256 + row)) * NB + tn * 256 + seg * 128;
#pragma unroll
        for (int i = 0; i < 16; i++) {
            int chunk = seg * 16 + i;
            *(short8*)&OutH[gb + i * 8] =
                *(const short8*)&R[row * 256 + ((chunk ^ (row & 7)) << 3)];
        }
    } else {
        // epilogue: fused combine: out[s] = gate[s]*(acc + b2), row scatter
        float bv[NI];
#pragma unroll
        for (int ni = 0; ni < NI; ni++)
            bv[ni] = bias[e * NB + tn * BN + wn * WN + ni * 16 + fr];
#pragma unroll
        for (int mi = 0; mi < 8; mi++) {
#pragma unroll
            for (int j = 0; j < 4; j++) {
                int r = tm * 256 + wm * 128 + mi * 16 + kq * 4 + j;
                int s = srcmap[e * CAP + r];
                if (s < 0) continue;
                float g = gate[s];
                float* ob = OutF + (size_t)s * NB + tn * BN + wn * WN;
#pragma unroll
                for (int ni = 0; ni < NI; ni++)
                    ob[ni * 16 + fr] = g * (acc[mi][ni][j] + bv[ni]);
            }
        }
    }
}

extern "C" void kernel_launch(void* const* d_in, const int* in_sizes, int n_in,
                              void* d_out, int out_size, void* d_ws, size_t ws_size,
                              hipStream_t stream) {
    const float* x  = (const float*)d_in[0];  // [S, M]
    const float* wg = (const float*)d_in[1];  // [M, E]
    const float* w1 = (const float*)d_in[2];  // [E, M, F]
    const float* b1 = (const float*)d_in[3];  // [E, F]
    const float* w2 = (const float*)d_in[4];  // [E, F, M]
    const float* b2 = (const float*)d_in[5];  // [E, M]
    float* out = (float*)d_out;

    char* ws = (char*)d_ws;
    unsigned short* A1  = (unsigned short*)(ws);                       // 16 MiB [E*C][M]
    unsigned short* W1T = (unsigned short*)(ws + (size_t)(16u << 20)); // 64 MiB [E][F][M]
    unsigned short* W2T = (unsigned short*)(ws + (size_t)(80u << 20)); // 64 MiB [E][M][F]
    unsigned short* H   = (unsigned short*)(ws + (size_t)(144u << 20));// 64 MiB [E][C][F]
    int*   idx  = (int*)(ws + (size_t)(208u << 20));
    float* gate = (float*)(ws + (size_t)(208u << 20) + 32768);
    int*   srcm = (int*)(ws + (size_t)(208u << 20) + 65536);

    hipMemsetAsync(d_out, 0, (size_t)S_TOK * M_DIM * sizeof(float), stream);

    gating_kernel<<<S_TOK / 4, 256, 0, stream>>>(x, wg, idx, gate);
    scan_build<<<1, 1024, 0, stream>>>(idx, srcm);
    dispatch_kernel<<<E_NUM * CAP, 256, 0, stream>>>(x, srcm, A1);
    transpose_cvt<<<dim3(F_DIM / 32, M_DIM / 32, E_NUM), dim3(32, 8), 0, stream>>>(
        w1, W1T, M_DIM, F_DIM);
    transpose_cvt<<<dim3(M_DIM / 32, F_DIM / 32, E_NUM), dim3(32, 8), 0, stream>>>(
        w2, W2T, F_DIM, M_DIM);

    // GEMM1: H = gelu(A1 @ w1 + b1)  256x256 tiles, K=1024; 512 blocks
    gemm8p<0><<<512, 512, 0, stream>>>(A1, W1T, b1, H, nullptr, nullptr, nullptr);

    // GEMM2: out[s] = gate[s]*(H @ w2 + b2)  256x128 tiles, K=4096; 256 blocks
    gemm8p<1><<<256, 512, 0, stream>>>(H, W2T, b2, nullptr, out, srcm, gate);
}